// Round 6
// baseline (1026.069 us; speedup 1.0000x reference)
//
#include <hip/hip_runtime.h>

#define N_V   11965
#define N_HE  189
#define NPAIR 35895
#define BB    256
#define SS    400
#define DD    128
#define BSR   102400   // B*S rows

typedef __bf16 bf16x8 __attribute__((ext_vector_type(8)));
typedef float  f32x4  __attribute__((ext_vector_type(4)));

__device__ __forceinline__ ushort f2bf(float f) {
    unsigned x = __float_as_uint(f);
    return (ushort)((x + 0x7FFFu + ((x >> 16) & 1u)) >> 16);
}
__device__ __forceinline__ float bf2f(ushort u) { return __uint_as_float(((unsigned)u) << 16); }
__device__ __forceinline__ float sigm(float x) { return 1.f / (1.f + __expf(-x)); }
__device__ __forceinline__ float tanh_f(float x) { return 2.f * sigm(2.f * x) - 1.f; }

// ---------------------------------------------------------------------------
// P1: fused prep — BN affine fold, e_deg count, weight transposes (fp32->bf16),
// per-table small GEMMs (edW/epW/cW/cdW/a_gi), pred_s dot folds. All fp32 in.
// ---------------------------------------------------------------------------
struct P1Args {
    const int* pair_e;
    const float *b1, *g1, *be1, *m1, *v1;
    const float *b2, *g2, *be2, *m2, *v2;
    const float *W1, *W2, *Wi, *Wg;
    const float *ed_t, *ep_t, *c_t, *cd_t, *a_t, *bi, *bg;
    const float *ha_t, *ca_t, *as_t, *it_t, *Ws;
    int* e_deg;
    float* aff;          // s1[128], t1[128], s2[128], t2[128]
    ushort *W1T, *W2T, *WiTe, *WgT;
    float *edW, *epW, *cW, *cdW, *agi, *sd;
};

__global__ __launch_bounds__(384) void p1_kernel(P1Args A) {
    int bid = blockIdx.x, t = threadIdx.x;
    if (bid == 0) {  // BN affine fold: BN(u) = u*s + (b*s + be - m*s)
        if (t < 128) {
            float s = A.g1[t] * rsqrtf(A.v1[t] + 1e-5f);
            A.aff[t] = s;
            A.aff[128 + t] = A.b1[t] * s + A.be1[t] - A.m1[t] * s;
        } else if (t < 256) {
            int d = t - 128;
            float s = A.g2[d] * rsqrtf(A.v2[d] + 1e-5f);
            A.aff[256 + d] = s;
            A.aff[384 + d] = A.b2[d] * s + A.be2[d] - A.m2[d] * s;
        }
        return;
    }
    bid -= 1;
    if (bid < 94) {  // e_deg count
        int p = bid * 384 + t;
        if (p < NPAIR) atomicAdd(&A.e_deg[A.pair_e[p]], 1);
        return;
    }
    bid -= 94;
    if (bid < 43) {  // W1T[n][k] = bf16(W1[k][n])
        int i = bid * 384 + t;
        if (i < 16384) { int k = i >> 7, n = i & 127; A.W1T[n * 128 + k] = f2bf(A.W1[i]); }
        return;
    }
    bid -= 43;
    if (bid < 43) {  // W2T
        int i = bid * 384 + t;
        if (i < 16384) { int k = i >> 7, n = i & 127; A.W2T[n * 128 + k] = f2bf(A.W2[i]); }
        return;
    }
    bid -= 43;
    if (bid < 43) {  // WiTe (Wi rows 0..127)
        int i = bid * 384 + t;
        if (i < 16384) { int k = i >> 7, n = i & 127; A.WiTe[n * 128 + k] = f2bf(A.Wi[i]); }
        return;
    }
    bid -= 43;
    if (bid < 128) {  // WgT (Wg rows 0..127, N=384)
        int i = bid * 384 + t;
        if (i < 49152) { int k = i / 384, n = i % 384; A.WgT[n * 128 + k] = f2bf(A.Wg[i]); }
        return;
    }
    bid -= 128;
    if (bid < 101) {  // edW = ed_table @ Wi[128:256] + bi
        if (t < 128) {
            float acc = 0.f;
            for (int k = 0; k < 128; ++k)
                acc += A.ed_t[bid * 128 + k] * A.Wi[(128 + k) * 128 + t];
            A.edW[bid * 128 + t] = acc + A.bi[t];
        }
        return;
    }
    bid -= 101;
    if (bid < 101) {  // epW = ep_table @ Wi[256:384]
        if (t < 128) {
            float acc = 0.f;
            for (int k = 0; k < 128; ++k)
                acc += A.ep_t[bid * 128 + k] * A.Wi[(256 + k) * 128 + t];
            A.epW[bid * 128 + t] = acc;
        }
        return;
    }
    bid -= 101;
    if (bid < 189) {  // cW = c_table @ Wi[384:512]
        if (t < 128) {
            float acc = 0.f;
            for (int k = 0; k < 128; ++k)
                acc += A.c_t[bid * 128 + k] * A.Wi[(384 + k) * 128 + t];
            A.cW[bid * 128 + t] = acc;
        }
        return;
    }
    bid -= 189;
    if (bid < 101) {  // cdW = cd_table @ Wi[512:640]
        if (t < 128) {
            float acc = 0.f;
            for (int k = 0; k < 128; ++k)
                acc += A.cd_t[bid * 128 + k] * A.Wi[(512 + k) * 128 + t];
            A.cdW[bid * 128 + t] = acc;
        }
        return;
    }
    bid -= 101;
    if (bid < 2) {  // a_gi = a_table @ Wg[128:256] + bg  (2 x 384)
        float acc = 0.f;
        for (int k = 0; k < 128; ++k)
            acc += A.a_t[bid * 128 + k] * A.Wg[(128 + k) * 384 + t];
        A.agi[bid * 384 + t] = acc + A.bg[t];
        return;
    }
    bid -= 2;
    {  // sdots: 38 blocks — per-table Ws dot folds
        int r = bid;
        const float* tab; int woff, row;
        if (r < 11)      { tab = A.ha_t; row = r;      woff = 0;   }
        else if (r < 22) { tab = A.ca_t; row = r - 11; woff = 128; }
        else if (r < 30) { tab = A.as_t; row = r - 22; woff = 256; }
        else             { tab = A.it_t; row = r - 30; woff = 384; }
        if (t < 64) {
            float p = tab[row * 128 + t] * A.Ws[woff + t]
                    + tab[row * 128 + 64 + t] * A.Ws[woff + 64 + t];
            #pragma unroll
            for (int o = 32; o > 0; o >>= 1) p += __shfl_xor(p, o);
            if (t == 0) A.sd[r] = p;
        }
    }
}

// fp32 -> bf16 convert (for e_table MFMA operand)
__global__ void cvt_kernel(const float* __restrict__ src, ushort* __restrict__ dst, int n) {
    int i = blockIdx.x * 256 + threadIdx.x;
    if (i < n) dst[i] = f2bf(src[i]);
}

// ---------------------------------------------------------------------------
// CSR build for edge->vertex gather (atomic-free edge means)
// ---------------------------------------------------------------------------
__global__ void csr_prefix(const int* __restrict__ e_deg, int* __restrict__ start) {
    __shared__ int sc[256];
    int t = threadIdx.x;
    int d = (t < N_HE) ? e_deg[t] : 0;
    sc[t] = d;
    __syncthreads();
    for (int off = 1; off < 256; off <<= 1) {
        int v = (t >= off) ? sc[t - off] : 0;
        __syncthreads();
        sc[t] += v;
        __syncthreads();
    }
    if (t < N_HE) start[t] = sc[t] - d;        // exclusive
    if (t == N_HE - 1) start[N_HE] = sc[t];    // total
}

__global__ void csr_fill(const int* __restrict__ pair_e, const int* __restrict__ pair_v,
                         const int* __restrict__ start, int* __restrict__ cursor,
                         int* __restrict__ list) {
    int p = blockIdx.x * 384 + threadIdx.x;
    if (p >= NPAIR) return;
    int e = pair_e[p];
    int pos = atomicAdd(&cursor[e], 1);
    list[start[e] + pos] = pair_v[p];
}

// ---------------------------------------------------------------------------
// Generic MFMA GEMM: out[M][N] = A[M][128] @ B[128][N], B given transposed
// (BT[n][k], bf16). Optional per-column affine (BN fold), per-row a_gi add.
// ---------------------------------------------------------------------------
template <int NT>
__global__ __launch_bounds__(256) void gemm_mfma(
    const ushort* __restrict__ Amat, const ushort* __restrict__ BT,
    float* __restrict__ out, int M,
    const float* __restrict__ colS, const float* __restrict__ colB,
    const float* __restrict__ agi, const int* __restrict__ aidx) {
    const int N = NT * 16;
    int lane = threadIdx.x & 63, wave = threadIdx.x >> 6;
    int q = lane >> 4, c = lane & 15;
    int rowbase = blockIdx.x * 64 + wave * 16;
    int arow = rowbase + c;
    if (arow > M - 1) arow = M - 1;  // clamp A loads; stores guarded
    f32x4 acc[NT];
#pragma unroll
    for (int i = 0; i < NT; ++i) acc[i] = (f32x4){0.f, 0.f, 0.f, 0.f};
#pragma unroll
    for (int ko = 0; ko < 4; ++ko) {
        bf16x8 af = *(const bf16x8*)(Amat + (size_t)arow * 128 + ko * 32 + q * 8);
#pragma unroll
        for (int nt = 0; nt < NT; ++nt) {
            bf16x8 bfr = *(const bf16x8*)(BT + (size_t)(nt * 16 + c) * 128 + ko * 32 + q * 8);
            acc[nt] = __builtin_amdgcn_mfma_f32_16x16x32_bf16(af, bfr, acc[nt], 0, 0, 0);
        }
    }
#pragma unroll
    for (int nt = 0; nt < NT; ++nt) {
        int col = nt * 16 + c;
        float s = colS ? colS[col] : 1.f;
        float bb = colB ? colB[col] : 0.f;
#pragma unroll
        for (int r = 0; r < 4; ++r) {
            int row = rowbase + q * 4 + r;
            if (row < M) {
                float v = acc[nt][r] * s + bb;
                if (agi) v += agi[aidx[row] * N + col];
                out[(size_t)row * N + col] = v;
            }
        }
    }
}

// ---------------------------------------------------------------------------
// Hypergraph smoothing
// ---------------------------------------------------------------------------
__global__ __launch_bounds__(512) void edge_mean(const float* __restrict__ Y,
                                                 const int* __restrict__ list,
                                                 const int* __restrict__ start,
                                                 float* __restrict__ E) {
    __shared__ float red[4][128];
    int e = blockIdx.x;
    int d = threadIdx.x & 127, g = threadIdx.x >> 7;
    int s0 = start[e], n = start[e + 1] - s0;
    float acc = 0.f;
    for (int i = g; i < n; i += 4) acc += Y[(size_t)list[s0 + i] * DD + d];
    red[g][d] = acc;
    __syncthreads();
    if (g == 0) {
        float v = red[0][d] + red[1][d] + red[2][d] + red[3][d];
        E[e * DD + d] = v / (float)(n > 0 ? n : 1);
    }
}

__global__ void v_mean(const float* __restrict__ E, const int* __restrict__ pair_e,
                       ushort* __restrict__ Xo, int relu) {
    int idx = blockIdx.x * 256 + threadIdx.x;
    if (idx >= N_V * DD) return;
    int v = idx >> 7, d = idx & 127;
    float a = E[pair_e[3 * v] * DD + d] + E[pair_e[3 * v + 1] * DD + d] +
              E[pair_e[3 * v + 2] * DD + d];
    a *= (1.f / 3.f);
    if (relu) a = fmaxf(a, 0.f);
    Xo[idx] = f2bf(a);
}

// ---------------------------------------------------------------------------
// K3: x = tanh(XW[e] + cW[ec[e]] + cdW[ecd[e]] + edW[ed] + epW[ep]) -> bf16
// ---------------------------------------------------------------------------
__global__ void k3_kernel(const int* __restrict__ in_e, const int* __restrict__ in_ed,
                          const int* __restrict__ in_ep, const float* __restrict__ XW,
                          const float* __restrict__ cW, const float* __restrict__ cdW,
                          const float* __restrict__ edW, const float* __restrict__ epW,
                          const int* __restrict__ ec_map, const int* __restrict__ ecd_map,
                          ushort* __restrict__ xbf) {
    int idx = blockIdx.x * 256 + threadIdx.x;
    if (idx >= BSR * DD) return;
    int row = idx >> 7, d = idx & 127;
    int e = in_e[row];
    float v = XW[(size_t)e * DD + d] + cW[ec_map[e] * DD + d] + cdW[ecd_map[e] * DD + d] +
              edW[in_ed[row] * DD + d] + epW[in_ep[row] * DD + d];
    xbf[idx] = f2bf(tanh_f(v));
}

// ---------------------------------------------------------------------------
// pred_s head (fp32 out)
// ---------------------------------------------------------------------------
__global__ void pred_s_kernel(const int* __restrict__ ha, const int* __restrict__ ca,
                              const int* __restrict__ as_, const int* __restrict__ it,
                              const float* __restrict__ sd, const float* __restrict__ bs,
                              float* __restrict__ out) {
    int i = blockIdx.x * 256 + threadIdx.x;
    if (i >= BSR) return;
    float v = sd[ha[i]] + sd[11 + ca[i]] + sd[22 + as_[i]] + sd[30 + it[i]] + bs[0];
    out[i] = sigm(v);
}

// ---------------------------------------------------------------------------
// GRU scan v5: 768 threads, split-K 2-way. Round-3..5 lesson: a local array
// with RUNTIME loop indices is committed to scratch by SROA (runs before
// unrolling) — asm pins and occupancy attributes can't undo that (r5's 31 ms
// first dispatch with +57 MB FETCH = the 50 MB scratch store, the smoking
// gun). Fix: 64 NAMED SCALARS, macro-unrolled loads/pins/FMAs, zero
// runtime-indexed locals -> true register residency.
// ---------------------------------------------------------------------------
__global__ void
__attribute__((amdgpu_flat_work_group_size(768, 768), amdgpu_waves_per_eu(2, 3)))
gru_scan(
    const float* __restrict__ gi, const ushort* __restrict__ xb,
    const float* __restrict__ Ug, const float* __restrict__ h0,
    const float* __restrict__ We, const float* __restrict__ beo_p,
    float* __restrict__ out) {
    __shared__ __align__(16) float h_s[128];
    __shared__ float pp1[384];    // khalf1 partials, all cols
    __shared__ float pp0h[128];   // khalf0 partials, cols 128..255 (r-cols)
    __shared__ float n_sL[128];
    __shared__ float p_s[128];
    int b = blockIdx.x, t = threadIdx.x;
    int khalf = (t >= 384) ? 1 : 0;
    int n = t - 384 * khalf;
    const float* up = Ug + (size_t)(khalf * 64) * 384 + n;
#define LD4(A, B, C, D, J0) \
    float A = up[(J0) * 384], B = up[(J0 + 1) * 384], C = up[(J0 + 2) * 384], \
          D = up[(J0 + 3) * 384];
    LD4(u0, u1, u2, u3, 0)     LD4(u4, u5, u6, u7, 4)
    LD4(u8, u9, u10, u11, 8)   LD4(u12, u13, u14, u15, 12)
    LD4(u16, u17, u18, u19, 16) LD4(u20, u21, u22, u23, 20)
    LD4(u24, u25, u26, u27, 24) LD4(u28, u29, u30, u31, 28)
    LD4(u32, u33, u34, u35, 32) LD4(u36, u37, u38, u39, 36)
    LD4(u40, u41, u42, u43, 40) LD4(u44, u45, u46, u47, 44)
    LD4(u48, u49, u50, u51, 48) LD4(u52, u53, u54, u55, 52)
    LD4(u56, u57, u58, u59, 56) LD4(u60, u61, u62, u63, 60)
#undef LD4
#define PIN4(A, B, C, D) \
    asm volatile("" : "+v"(A)); asm volatile("" : "+v"(B)); \
    asm volatile("" : "+v"(C)); asm volatile("" : "+v"(D));
    PIN4(u0, u1, u2, u3)     PIN4(u4, u5, u6, u7)
    PIN4(u8, u9, u10, u11)   PIN4(u12, u13, u14, u15)
    PIN4(u16, u17, u18, u19) PIN4(u20, u21, u22, u23)
    PIN4(u24, u25, u26, u27) PIN4(u28, u29, u30, u31)
    PIN4(u32, u33, u34, u35) PIN4(u36, u37, u38, u39)
    PIN4(u40, u41, u42, u43) PIN4(u44, u45, u46, u47)
    PIN4(u48, u49, u50, u51) PIN4(u52, u53, u54, u55)
    PIN4(u56, u57, u58, u59) PIN4(u60, u61, u62, u63)
#undef PIN4
    float beo = beo_p[0];
    float wev = 0.f;
    if (t < 128) { wev = We[t]; h_s[t] = h0[b * 128 + t]; }
    const float* gip = gi + (size_t)b * SS * 384;
    const ushort* xp = xb + (size_t)b * SS * 128;
    float gz_nx = 0.f, gr_nx = 0.f, gn_nx = 0.f, xw_nx = 0.f;
    if (t < 128) {
        gz_nx = gip[t];
        xw_nx = bf2f(xp[t]) * wev;
    } else if (t >= 256 && t < 384) {
        gr_nx = gip[t - 128];
        gn_nx = gip[t];
    }
    float* omain = out + BSR + b * SS;
    __syncthreads();
    for (int s = 0; s < SS; ++s) {
        float gz = gz_nx, gr = gr_nx, gn = gn_nx, xw = xw_nx;
        if (s + 1 < SS) {
            const float* g2 = gip + (size_t)(s + 1) * 384;
            if (t < 128) {
                gz_nx = g2[t];
                xw_nx = bf2f(xp[(size_t)(s + 1) * 128 + t]) * wev;
            } else if (t >= 256 && t < 384) {
                gr_nx = g2[t - 128];
                gn_nx = g2[t];
            }
        }
        // partial matvec over own K-half (h broadcast reads, wave-uniform)
        const float4* h4 = (const float4*)h_s + khalf * 16;
        float4 a4 = make_float4(0.f, 0.f, 0.f, 0.f);
#define FMA4(HJ, A, B, C, D) { float4 hv = h4[HJ]; \
        a4.x = fmaf(hv.x, A, a4.x); a4.y = fmaf(hv.y, B, a4.y); \
        a4.z = fmaf(hv.z, C, a4.z); a4.w = fmaf(hv.w, D, a4.w); }
        FMA4(0, u0, u1, u2, u3)      FMA4(1, u4, u5, u6, u7)
        FMA4(2, u8, u9, u10, u11)    FMA4(3, u12, u13, u14, u15)
        FMA4(4, u16, u17, u18, u19)  FMA4(5, u20, u21, u22, u23)
        FMA4(6, u24, u25, u26, u27)  FMA4(7, u28, u29, u30, u31)
        FMA4(8, u32, u33, u34, u35)  FMA4(9, u36, u37, u38, u39)
        FMA4(10, u40, u41, u42, u43) FMA4(11, u44, u45, u46, u47)
        FMA4(12, u48, u49, u50, u51) FMA4(13, u52, u53, u54, u55)
        FMA4(14, u56, u57, u58, u59) FMA4(15, u60, u61, u62, u63)
#undef FMA4
        float part = (a4.x + a4.y) + (a4.z + a4.w);
        if (khalf) pp1[n] = part;
        else if (t >= 128 && t < 256) pp0h[t - 128] = part;
        __syncthreads();
        float z = 0.f, h_old = 0.f;
        if (t < 128) {
            float gh = part + pp1[t];
            z = sigm(gz + gh);
            h_old = h_s[t];
            p_s[t] = h_old * xw;
        } else if (t >= 256 && t < 384) {
            float ghn = part + pp1[t];
            float ghr = pp0h[t - 256] + pp1[t - 128];
            float r = sigm(gr + ghr);
            n_sL[t - 256] = tanh_f(gn + r * ghn);
        }
        __syncthreads();
        if (t < 128) {
            h_s[t] = (1.f - z) * n_sL[t] + z * h_old;
        } else if (t >= 384 && t < 448) {  // wave 6: y reduction (pre-update h staged in p_s)
            int l = t - 384;
            float pv = p_s[l] + p_s[l + 64];
#pragma unroll
            for (int o = 32; o > 0; o >>= 1) pv += __shfl_xor(pv, o);
            if (l == 0) omain[s] = sigm(pv + beo);
        }
        __syncthreads();
    }
}

// ---------------------------------------------------------------------------
extern "C" void kernel_launch(void* const* d_in, const int* in_sizes, int n_in,
                              void* d_out, int out_size, void* d_ws, size_t ws_size,
                              hipStream_t stream) {
    const int* in_e   = (const int*)d_in[0];
    const int* in_ed  = (const int*)d_in[1];
    const int* in_ep  = (const int*)d_in[2];
    const int* in_a   = (const int*)d_in[3];
    const int* in_as  = (const int*)d_in[4];
    const int* in_ha  = (const int*)d_in[5];
    const int* in_ca  = (const int*)d_in[6];
    const int* in_it  = (const int*)d_in[7];
    const float* deliver_h = (const float*)d_in[8];
    const int* pair_v = (const int*)d_in[9];
    const int* pair_e = (const int*)d_in[10];
    const int* ec_map = (const int*)d_in[11];
    const int* ecd_map= (const int*)d_in[12];
    const float* e_table  = (const float*)d_in[13];
    const float* c_table  = (const float*)d_in[14];
    const float* ed_table = (const float*)d_in[15];
    const float* cd_table = (const float*)d_in[16];
    const float* a_table  = (const float*)d_in[17];
    const float* it_table = (const float*)d_in[18];
    const float* ep_table = (const float*)d_in[19];
    const float* ha_table = (const float*)d_in[20];
    const float* ca_table = (const float*)d_in[21];
    const float* as_table = (const float*)d_in[22];
    const float* W1 = (const float*)d_in[23];
    const float* b1 = (const float*)d_in[24];
    const float* g1 = (const float*)d_in[25];
    const float* be1= (const float*)d_in[26];
    const float* m1 = (const float*)d_in[27];
    const float* v1 = (const float*)d_in[28];
    const float* W2 = (const float*)d_in[29];
    const float* b2 = (const float*)d_in[30];
    const float* g2 = (const float*)d_in[31];
    const float* be2= (const float*)d_in[32];
    const float* m2 = (const float*)d_in[33];
    const float* v2 = (const float*)d_in[34];
    const float* Wi = (const float*)d_in[35];
    const float* bi = (const float*)d_in[36];
    const float* Wg = (const float*)d_in[37];
    const float* Ug = (const float*)d_in[38];
    const float* bg = (const float*)d_in[39];
    const float* We = (const float*)d_in[40];
    const float* beo= (const float*)d_in[41];
    const float* Ws = (const float*)d_in[42];
    const float* bs = (const float*)d_in[43];
    float* out = (float*)d_out;
    char* ws = (char*)d_ws;

    size_t off = 0;
    auto alloc = [&](size_t bytes) { size_t o = off; off += (bytes + 255) & ~(size_t)255; return o; };
    size_t o_degcur = alloc(378 * 4);            // e_deg[189] + cursor[189]
    size_t o_start  = alloc(190 * 4);
    size_t o_list   = alloc((size_t)NPAIR * 4);
    size_t o_aff    = alloc(512 * 4);
    size_t o_W1T    = alloc(16384 * 2);
    size_t o_W2T    = alloc(16384 * 2);
    size_t o_WiTe   = alloc(16384 * 2);
    size_t o_WgT    = alloc(49152 * 2);
    size_t o_edW    = alloc(101 * 128 * 4);
    size_t o_epW    = alloc(101 * 128 * 4);
    size_t o_cW     = alloc(189 * 128 * 4);
    size_t o_cdW    = alloc(101 * 128 * 4);
    size_t o_agi    = alloc(2 * 384 * 4);
    size_t o_sd     = alloc(38 * 4);
    size_t o_etb    = alloc((size_t)N_V * DD * 2);
    size_t o_E      = alloc((size_t)N_HE * DD * 4);
    size_t o_Y      = alloc((size_t)N_V * DD * 4);
    size_t o_X1     = alloc((size_t)N_V * DD * 2);
    size_t o_X2     = alloc((size_t)N_V * DD * 2);
    size_t o_XW     = alloc((size_t)N_V * DD * 4);
    size_t o_xbf    = alloc((size_t)BSR * DD * 2);
    size_t o_gi     = alloc((size_t)BSR * 384 * 4);

    int*    e_deg  = (int*)(ws + o_degcur);
    int*    cursor = e_deg + 189;
    int*    startp = (int*)(ws + o_start);
    int*    listp  = (int*)(ws + o_list);
    float*  aff    = (float*)(ws + o_aff);
    ushort* W1T    = (ushort*)(ws + o_W1T);
    ushort* W2T    = (ushort*)(ws + o_W2T);
    ushort* WiTe   = (ushort*)(ws + o_WiTe);
    ushort* WgT    = (ushort*)(ws + o_WgT);
    float*  edW    = (float*)(ws + o_edW);
    float*  epW    = (float*)(ws + o_epW);
    float*  cW     = (float*)(ws + o_cW);
    float*  cdW    = (float*)(ws + o_cdW);
    float*  agi    = (float*)(ws + o_agi);
    float*  sd     = (float*)(ws + o_sd);
    ushort* e_tb   = (ushort*)(ws + o_etb);
    float*  E      = (float*)(ws + o_E);
    float*  Y      = (float*)(ws + o_Y);
    ushort* X1b    = (ushort*)(ws + o_X1);
    ushort* X2b    = (ushort*)(ws + o_X2);
    float*  XW     = (float*)(ws + o_XW);
    ushort* xbf    = (ushort*)(ws + o_xbf);
    float*  gi     = (float*)(ws + o_gi);

    hipMemsetAsync(ws + o_degcur, 0, 378 * 4, stream);

    P1Args pa;
    pa.pair_e = pair_e;
    pa.b1 = b1; pa.g1 = g1; pa.be1 = be1; pa.m1 = m1; pa.v1 = v1;
    pa.b2 = b2; pa.g2 = g2; pa.be2 = be2; pa.m2 = m2; pa.v2 = v2;
    pa.W1 = W1; pa.W2 = W2; pa.Wi = Wi; pa.Wg = Wg;
    pa.ed_t = ed_table; pa.ep_t = ep_table; pa.c_t = c_table; pa.cd_t = cd_table;
    pa.a_t = a_table; pa.bi = bi; pa.bg = bg;
    pa.ha_t = ha_table; pa.ca_t = ca_table; pa.as_t = as_table; pa.it_t = it_table; pa.Ws = Ws;
    pa.e_deg = e_deg; pa.aff = aff;
    pa.W1T = W1T; pa.W2T = W2T; pa.WiTe = WiTe; pa.WgT = WgT;
    pa.edW = edW; pa.epW = epW; pa.cW = cW; pa.cdW = cdW; pa.agi = agi; pa.sd = sd;
    p1_kernel<<<884, 384, 0, stream>>>(pa);

    cvt_kernel<<<(N_V * DD + 255) / 256, 256, 0, stream>>>(e_table, e_tb, N_V * DD);
    csr_prefix<<<1, 256, 0, stream>>>(e_deg, startp);
    csr_fill<<<94, 384, 0, stream>>>(pair_e, pair_v, startp, cursor, listp);

    pred_s_kernel<<<(BSR + 255) / 256, 256, 0, stream>>>(in_ha, in_ca, in_as, in_it, sd, bs, out);

    // conv1: Y = BN1(e_table @ W1 + b1)
    gemm_mfma<8><<<(N_V + 63) / 64, 256, 0, stream>>>(e_tb, W1T, Y, N_V, aff, aff + 128,
                                                      nullptr, nullptr);
    edge_mean<<<N_HE, 512, 0, stream>>>(Y, listp, startp, E);
    v_mean<<<(N_V * DD + 255) / 256, 256, 0, stream>>>(E, pair_e, X1b, 1);
    // conv2
    gemm_mfma<8><<<(N_V + 63) / 64, 256, 0, stream>>>(X1b, W2T, Y, N_V, aff + 256, aff + 384,
                                                      nullptr, nullptr);
    edge_mean<<<N_HE, 512, 0, stream>>>(Y, listp, startp, E);
    v_mean<<<(N_V * DD + 255) / 256, 256, 0, stream>>>(E, pair_e, X2b, 0);
    // XW = X2 @ Wi_e
    gemm_mfma<8><<<(N_V + 63) / 64, 256, 0, stream>>>(X2b, WiTe, XW, N_V, nullptr, nullptr,
                                                      nullptr, nullptr);
    // x = tanh(5-way gather sum)
    k3_kernel<<<(BSR * DD + 255) / 256, 256, 0, stream>>>(in_e, in_ed, in_ep, XW, cW, cdW, edW,
                                                          epW, ec_map, ecd_map, xbf);
    // gi = x @ Wg_x + a_gi[input_a]
    gemm_mfma<24><<<BSR / 64, 256, 0, stream>>>(xbf, WgT, gi, BSR, nullptr, nullptr, agi, in_a);
    // GRU scan + pred_main
    gru_scan<<<BB, 768, 0, stream>>>(gi, xbf, Ug, deliver_h, We, beo, out);
}

// Round 7
// 1011.138 us; speedup vs baseline: 1.0148x; 1.0148x over previous
//
#include <hip/hip_runtime.h>

#define N_V   11965
#define N_HE  189
#define NPAIR 35895
#define BB    256
#define SS    400
#define DD    128
#define BSR   102400   // B*S rows

typedef __bf16 bf16x8 __attribute__((ext_vector_type(8)));
typedef float  f32x4  __attribute__((ext_vector_type(4)));

__device__ __forceinline__ ushort f2bf(float f) {
    unsigned x = __float_as_uint(f);
    return (ushort)((x + 0x7FFFu + ((x >> 16) & 1u)) >> 16);
}
__device__ __forceinline__ float bf2f(ushort u) { return __uint_as_float(((unsigned)u) << 16); }
__device__ __forceinline__ float sigm(float x) { return 1.f / (1.f + __expf(-x)); }
__device__ __forceinline__ float tanh_f(float x) { return 2.f * sigm(2.f * x) - 1.f; }
// packed-bf16 unpack: low half = shift; high half = reinterpret (junk low mantissa
// bits perturb products by ~2^-17 relative — negligible vs bf16's 2^-8 quantum).
__device__ __forceinline__ float blo(unsigned u) { return __uint_as_float(u << 16); }
__device__ __forceinline__ float bhi(unsigned u) { return __uint_as_float(u); }

// ---------------------------------------------------------------------------
// P1: fused prep — BN affine fold, e_deg count, weight transposes (fp32->bf16),
// per-table small GEMMs (edW/epW/cW/cdW/a_gi), pred_s dot folds. All fp32 in.
// ---------------------------------------------------------------------------
struct P1Args {
    const int* pair_e;
    const float *b1, *g1, *be1, *m1, *v1;
    const float *b2, *g2, *be2, *m2, *v2;
    const float *W1, *W2, *Wi, *Wg, *Ug;
    const float *ed_t, *ep_t, *c_t, *cd_t, *a_t, *bi, *bg;
    const float *ha_t, *ca_t, *as_t, *it_t, *Ws;
    int* e_deg;
    float* aff;          // s1[128], t1[128], s2[128], t2[128]
    ushort *W1T, *W2T, *WiTe, *WgT, *UgT;
    float *edW, *epW, *cW, *cdW, *agi, *sd;
};

__global__ __launch_bounds__(384) void p1_kernel(P1Args A) {
    int bid = blockIdx.x, t = threadIdx.x;
    if (bid == 0) {  // BN affine fold: BN(u) = u*s + (b*s + be - m*s)
        if (t < 128) {
            float s = A.g1[t] * rsqrtf(A.v1[t] + 1e-5f);
            A.aff[t] = s;
            A.aff[128 + t] = A.b1[t] * s + A.be1[t] - A.m1[t] * s;
        } else if (t < 256) {
            int d = t - 128;
            float s = A.g2[d] * rsqrtf(A.v2[d] + 1e-5f);
            A.aff[256 + d] = s;
            A.aff[384 + d] = A.b2[d] * s + A.be2[d] - A.m2[d] * s;
        }
        return;
    }
    bid -= 1;
    if (bid < 94) {  // e_deg count
        int p = bid * 384 + t;
        if (p < NPAIR) atomicAdd(&A.e_deg[A.pair_e[p]], 1);
        return;
    }
    bid -= 94;
    if (bid < 43) {  // W1T[n][k] = bf16(W1[k][n])
        int i = bid * 384 + t;
        if (i < 16384) { int k = i >> 7, n = i & 127; A.W1T[n * 128 + k] = f2bf(A.W1[i]); }
        return;
    }
    bid -= 43;
    if (bid < 43) {  // W2T
        int i = bid * 384 + t;
        if (i < 16384) { int k = i >> 7, n = i & 127; A.W2T[n * 128 + k] = f2bf(A.W2[i]); }
        return;
    }
    bid -= 43;
    if (bid < 43) {  // WiTe (Wi rows 0..127)
        int i = bid * 384 + t;
        if (i < 16384) { int k = i >> 7, n = i & 127; A.WiTe[n * 128 + k] = f2bf(A.Wi[i]); }
        return;
    }
    bid -= 43;
    if (bid < 128) {  // WgT (Wg rows 0..127, N=384)
        int i = bid * 384 + t;
        if (i < 49152) { int k = i / 384, n = i % 384; A.WgT[n * 128 + k] = f2bf(A.Wg[i]); }
        return;
    }
    bid -= 128;
    if (bid < 128) {  // UgT[n][k] = bf16(Ug[k][n])  (Ug: 128x384)
        int i = bid * 384 + t;
        if (i < 49152) { int k = i / 384, n = i % 384; A.UgT[n * 128 + k] = f2bf(A.Ug[i]); }
        return;
    }
    bid -= 128;
    if (bid < 101) {  // edW = ed_table @ Wi[128:256] + bi
        if (t < 128) {
            float acc = 0.f;
            for (int k = 0; k < 128; ++k)
                acc += A.ed_t[bid * 128 + k] * A.Wi[(128 + k) * 128 + t];
            A.edW[bid * 128 + t] = acc + A.bi[t];
        }
        return;
    }
    bid -= 101;
    if (bid < 101) {  // epW = ep_table @ Wi[256:384]
        if (t < 128) {
            float acc = 0.f;
            for (int k = 0; k < 128; ++k)
                acc += A.ep_t[bid * 128 + k] * A.Wi[(256 + k) * 128 + t];
            A.epW[bid * 128 + t] = acc;
        }
        return;
    }
    bid -= 101;
    if (bid < 189) {  // cW = c_table @ Wi[384:512]
        if (t < 128) {
            float acc = 0.f;
            for (int k = 0; k < 128; ++k)
                acc += A.c_t[bid * 128 + k] * A.Wi[(384 + k) * 128 + t];
            A.cW[bid * 128 + t] = acc;
        }
        return;
    }
    bid -= 189;
    if (bid < 101) {  // cdW = cd_table @ Wi[512:640]
        if (t < 128) {
            float acc = 0.f;
            for (int k = 0; k < 128; ++k)
                acc += A.cd_t[bid * 128 + k] * A.Wi[(512 + k) * 128 + t];
            A.cdW[bid * 128 + t] = acc;
        }
        return;
    }
    bid -= 101;
    if (bid < 2) {  // a_gi = a_table @ Wg[128:256] + bg  (2 x 384)
        float acc = 0.f;
        for (int k = 0; k < 128; ++k)
            acc += A.a_t[bid * 128 + k] * A.Wg[(128 + k) * 384 + t];
        A.agi[bid * 384 + t] = acc + A.bg[t];
        return;
    }
    bid -= 2;
    {  // sdots: 38 blocks — per-table Ws dot folds
        int r = bid;
        const float* tab; int woff, row;
        if (r < 11)      { tab = A.ha_t; row = r;      woff = 0;   }
        else if (r < 22) { tab = A.ca_t; row = r - 11; woff = 128; }
        else if (r < 30) { tab = A.as_t; row = r - 22; woff = 256; }
        else             { tab = A.it_t; row = r - 30; woff = 384; }
        if (t < 64) {
            float p = tab[row * 128 + t] * A.Ws[woff + t]
                    + tab[row * 128 + 64 + t] * A.Ws[woff + 64 + t];
            #pragma unroll
            for (int o = 32; o > 0; o >>= 1) p += __shfl_xor(p, o);
            if (t == 0) A.sd[r] = p;
        }
    }
}

// fp32 -> bf16 convert (for e_table MFMA operand)
__global__ void cvt_kernel(const float* __restrict__ src, ushort* __restrict__ dst, int n) {
    int i = blockIdx.x * 256 + threadIdx.x;
    if (i < n) dst[i] = f2bf(src[i]);
}

// ---------------------------------------------------------------------------
// CSR build for edge->vertex gather (atomic-free edge means)
// ---------------------------------------------------------------------------
__global__ void csr_prefix(const int* __restrict__ e_deg, int* __restrict__ start) {
    __shared__ int sc[256];
    int t = threadIdx.x;
    int d = (t < N_HE) ? e_deg[t] : 0;
    sc[t] = d;
    __syncthreads();
    for (int off = 1; off < 256; off <<= 1) {
        int v = (t >= off) ? sc[t - off] : 0;
        __syncthreads();
        sc[t] += v;
        __syncthreads();
    }
    if (t < N_HE) start[t] = sc[t] - d;        // exclusive
    if (t == N_HE - 1) start[N_HE] = sc[t];    // total
}

__global__ void csr_fill(const int* __restrict__ pair_e, const int* __restrict__ pair_v,
                         const int* __restrict__ start, int* __restrict__ cursor,
                         int* __restrict__ list) {
    int p = blockIdx.x * 384 + threadIdx.x;
    if (p >= NPAIR) return;
    int e = pair_e[p];
    int pos = atomicAdd(&cursor[e], 1);
    list[start[e] + pos] = pair_v[p];
}

// ---------------------------------------------------------------------------
// Generic MFMA GEMM: out[M][N] = A[M][128] @ B[128][N], B given transposed
// (BT[n][k], bf16). Optional per-column affine (BN fold), per-row a_gi add.
// ---------------------------------------------------------------------------
template <int NT>
__global__ __launch_bounds__(256) void gemm_mfma(
    const ushort* __restrict__ Amat, const ushort* __restrict__ BT,
    float* __restrict__ out, int M,
    const float* __restrict__ colS, const float* __restrict__ colB,
    const float* __restrict__ agi, const int* __restrict__ aidx) {
    const int N = NT * 16;
    int lane = threadIdx.x & 63, wave = threadIdx.x >> 6;
    int q = lane >> 4, c = lane & 15;
    int rowbase = blockIdx.x * 64 + wave * 16;
    int arow = rowbase + c;
    if (arow > M - 1) arow = M - 1;  // clamp A loads; stores guarded
    f32x4 acc[NT];
#pragma unroll
    for (int i = 0; i < NT; ++i) acc[i] = (f32x4){0.f, 0.f, 0.f, 0.f};
#pragma unroll
    for (int ko = 0; ko < 4; ++ko) {
        bf16x8 af = *(const bf16x8*)(Amat + (size_t)arow * 128 + ko * 32 + q * 8);
#pragma unroll
        for (int nt = 0; nt < NT; ++nt) {
            bf16x8 bfr = *(const bf16x8*)(BT + (size_t)(nt * 16 + c) * 128 + ko * 32 + q * 8);
            acc[nt] = __builtin_amdgcn_mfma_f32_16x16x32_bf16(af, bfr, acc[nt], 0, 0, 0);
        }
    }
#pragma unroll
    for (int nt = 0; nt < NT; ++nt) {
        int col = nt * 16 + c;
        float s = colS ? colS[col] : 1.f;
        float bb = colB ? colB[col] : 0.f;
#pragma unroll
        for (int r = 0; r < 4; ++r) {
            int row = rowbase + q * 4 + r;
            if (row < M) {
                float v = acc[nt][r] * s + bb;
                if (agi) v += agi[aidx[row] * N + col];
                out[(size_t)row * N + col] = v;
            }
        }
    }
}

// ---------------------------------------------------------------------------
// Hypergraph smoothing
// ---------------------------------------------------------------------------
__global__ __launch_bounds__(512) void edge_mean(const float* __restrict__ Y,
                                                 const int* __restrict__ list,
                                                 const int* __restrict__ start,
                                                 float* __restrict__ E) {
    __shared__ float red[4][128];
    int e = blockIdx.x;
    int d = threadIdx.x & 127, g = threadIdx.x >> 7;
    int s0 = start[e], n = start[e + 1] - s0;
    float acc = 0.f;
    for (int i = g; i < n; i += 4) acc += Y[(size_t)list[s0 + i] * DD + d];
    red[g][d] = acc;
    __syncthreads();
    if (g == 0) {
        float v = red[0][d] + red[1][d] + red[2][d] + red[3][d];
        E[e * DD + d] = v / (float)(n > 0 ? n : 1);
    }
}

__global__ void v_mean(const float* __restrict__ E, const int* __restrict__ pair_e,
                       ushort* __restrict__ Xo, int relu) {
    int idx = blockIdx.x * 256 + threadIdx.x;
    if (idx >= N_V * DD) return;
    int v = idx >> 7, d = idx & 127;
    float a = E[pair_e[3 * v] * DD + d] + E[pair_e[3 * v + 1] * DD + d] +
              E[pair_e[3 * v + 2] * DD + d];
    a *= (1.f / 3.f);
    if (relu) a = fmaxf(a, 0.f);
    Xo[idx] = f2bf(a);
}

// ---------------------------------------------------------------------------
// K3: x = tanh(XW[e] + cW[ec[e]] + cdW[ecd[e]] + edW[ed] + epW[ep]) -> bf16
// ---------------------------------------------------------------------------
__global__ void k3_kernel(const int* __restrict__ in_e, const int* __restrict__ in_ed,
                          const int* __restrict__ in_ep, const float* __restrict__ XW,
                          const float* __restrict__ cW, const float* __restrict__ cdW,
                          const float* __restrict__ edW, const float* __restrict__ epW,
                          const int* __restrict__ ec_map, const int* __restrict__ ecd_map,
                          ushort* __restrict__ xbf) {
    int idx = blockIdx.x * 256 + threadIdx.x;
    if (idx >= BSR * DD) return;
    int row = idx >> 7, d = idx & 127;
    int e = in_e[row];
    float v = XW[(size_t)e * DD + d] + cW[ec_map[e] * DD + d] + cdW[ecd_map[e] * DD + d] +
              edW[in_ed[row] * DD + d] + epW[in_ep[row] * DD + d];
    xbf[idx] = f2bf(tanh_f(v));
}

// ---------------------------------------------------------------------------
// pred_s head (fp32 out)
// ---------------------------------------------------------------------------
__global__ void pred_s_kernel(const int* __restrict__ ha, const int* __restrict__ ca,
                              const int* __restrict__ as_, const int* __restrict__ it,
                              const float* __restrict__ sd, const float* __restrict__ bs,
                              float* __restrict__ out) {
    int i = blockIdx.x * 256 + threadIdx.x;
    if (i >= BSR) return;
    float v = sd[ha[i]] + sd[11 + ca[i]] + sd[22 + as_[i]] + sd[30 + it[i]] + bs[0];
    out[i] = sigm(v);
}

// ---------------------------------------------------------------------------
// GRU scan v6: 768 threads. Thread t: K-quarter kq=t/192 (wave-uniform,
// 192=3 waves), columns cp=t%192 and cp+192. Weights: 64 bf16 packed into
// 16 named uint scalars (under the empirically observed ~56-68 VGPR clamp
// that defeated rounds 3-6). Pins INSIDE the loop make the 16 uints
// loop-carried asm values: blocks load-sinking, blocks LICM of the unpacks,
// and forces residency. h reads halved: 8 ds_read_b128/wave/step (K-quarter).
// Partials staged to pp[4][392] (pad 8 -> conflict-free gate sums).
// ---------------------------------------------------------------------------
__global__ void
__attribute__((amdgpu_flat_work_group_size(768, 768), amdgpu_waves_per_eu(2, 3)))
gru_scan(
    const float* __restrict__ gi, const ushort* __restrict__ xb,
    const ushort* __restrict__ UgT, const float* __restrict__ h0,
    const float* __restrict__ We, const float* __restrict__ beo_p,
    float* __restrict__ out) {
    __shared__ __align__(16) float h_s[128];
    __shared__ float pp[4][392];   // [kq][col], pad 8 to spread banks
    __shared__ float n_sL[128];
    __shared__ float p_s[128];
    int b = blockIdx.x, t = threadIdx.x;
    int kq = t / 192;
    int cp = t % 192;
    const unsigned* WA = (const unsigned*)(UgT + (size_t)cp * 128 + kq * 32);
    const unsigned* WB = (const unsigned*)(UgT + (size_t)(cp + 192) * 128 + kq * 32);
    unsigned a0 = WA[0], a1 = WA[1], a2 = WA[2], a3 = WA[3], a4 = WA[4], a5 = WA[5],
             a6 = WA[6], a7 = WA[7], a8 = WA[8], a9 = WA[9], a10 = WA[10], a11 = WA[11],
             a12 = WA[12], a13 = WA[13], a14 = WA[14], a15 = WA[15];
    unsigned c0 = WB[0], c1 = WB[1], c2 = WB[2], c3 = WB[3], c4 = WB[4], c5 = WB[5],
             c6 = WB[6], c7 = WB[7], c8 = WB[8], c9 = WB[9], c10 = WB[10], c11 = WB[11],
             c12 = WB[12], c13 = WB[13], c14 = WB[14], c15 = WB[15];
    float beo = beo_p[0];
    float wev = 0.f;
    if (t < 128) { wev = We[t]; h_s[t] = h0[b * 128 + t]; }
    const float* gip = gi + (size_t)b * SS * 384;
    const ushort* xp = xb + (size_t)b * SS * 128;
    float gz_nx = 0.f, gr_nx = 0.f, gn_nx = 0.f, xw_nx = 0.f;
    if (t < 128) {
        gz_nx = gip[t];
        xw_nx = bf2f(xp[t]) * wev;
    } else if (t >= 256 && t < 384) {
        gr_nx = gip[t - 128];
        gn_nx = gip[t];
    }
    float* omain = out + BSR + b * SS;
    __syncthreads();
    for (int s = 0; s < SS; ++s) {
        // loop-carried pins: weights must be in VGPRs here every iteration
#define PIN(X) asm volatile("" : "+v"(X));
        PIN(a0) PIN(a1) PIN(a2) PIN(a3) PIN(a4) PIN(a5) PIN(a6) PIN(a7)
        PIN(a8) PIN(a9) PIN(a10) PIN(a11) PIN(a12) PIN(a13) PIN(a14) PIN(a15)
        PIN(c0) PIN(c1) PIN(c2) PIN(c3) PIN(c4) PIN(c5) PIN(c6) PIN(c7)
        PIN(c8) PIN(c9) PIN(c10) PIN(c11) PIN(c12) PIN(c13) PIN(c14) PIN(c15)
#undef PIN
        float gz = gz_nx, gr = gr_nx, gn = gn_nx, xw = xw_nx;
        if (s + 1 < SS) {
            const float* g2 = gip + (size_t)(s + 1) * 384;
            if (t < 128) {
                gz_nx = g2[t];
                xw_nx = bf2f(xp[(size_t)(s + 1) * 128 + t]) * wev;
            } else if (t >= 256 && t < 384) {
                gr_nx = g2[t - 128];
                gn_nx = g2[t];
            }
        }
        // partial matvec: 2 columns x 32 k (own K-quarter), h via 8 uniform b128
        const float4* h4 = (const float4*)h_s + kq * 8;
        float accA = 0.f, accB = 0.f;
#define FB(I, UL, UH, VL, VH) { float4 hv = h4[I]; \
        accA = fmaf(hv.x, blo(UL), accA); accA = fmaf(hv.y, bhi(UL), accA); \
        accA = fmaf(hv.z, blo(UH), accA); accA = fmaf(hv.w, bhi(UH), accA); \
        accB = fmaf(hv.x, blo(VL), accB); accB = fmaf(hv.y, bhi(VL), accB); \
        accB = fmaf(hv.z, blo(VH), accB); accB = fmaf(hv.w, bhi(VH), accB); }
        FB(0, a0, a1, c0, c1)    FB(1, a2, a3, c2, c3)
        FB(2, a4, a5, c4, c5)    FB(3, a6, a7, c6, c7)
        FB(4, a8, a9, c8, c9)    FB(5, a10, a11, c10, c11)
        FB(6, a12, a13, c12, c13) FB(7, a14, a15, c14, c15)
#undef FB
        pp[kq][cp] = accA;
        pp[kq][cp + 192] = accB;
        __syncthreads();
        float z = 0.f, h_old = 0.f;
        if (t < 128) {
            float S = pp[0][t] + pp[1][t] + pp[2][t] + pp[3][t];
            z = sigm(gz + S);
            h_old = h_s[t];
            p_s[t] = h_old * xw;
        } else if (t >= 256 && t < 384) {
            int j = t - 256;
            float Sr = pp[0][128 + j] + pp[1][128 + j] + pp[2][128 + j] + pp[3][128 + j];
            float Sn = pp[0][256 + j] + pp[1][256 + j] + pp[2][256 + j] + pp[3][256 + j];
            float r = sigm(gr + Sr);
            n_sL[j] = tanh_f(gn + r * Sn);
        }
        __syncthreads();
        if (t < 128) {
            h_s[t] = (1.f - z) * n_sL[t] + z * h_old;
        } else if (t >= 384 && t < 448) {  // wave 6: y reduction (pre-update h in p_s)
            int l = t - 384;
            float pv = p_s[l] + p_s[l + 64];
#pragma unroll
            for (int o = 32; o > 0; o >>= 1) pv += __shfl_xor(pv, o);
            if (l == 0) omain[s] = sigm(pv + beo);
        }
        __syncthreads();
    }
}

// ---------------------------------------------------------------------------
extern "C" void kernel_launch(void* const* d_in, const int* in_sizes, int n_in,
                              void* d_out, int out_size, void* d_ws, size_t ws_size,
                              hipStream_t stream) {
    const int* in_e   = (const int*)d_in[0];
    const int* in_ed  = (const int*)d_in[1];
    const int* in_ep  = (const int*)d_in[2];
    const int* in_a   = (const int*)d_in[3];
    const int* in_as  = (const int*)d_in[4];
    const int* in_ha  = (const int*)d_in[5];
    const int* in_ca  = (const int*)d_in[6];
    const int* in_it  = (const int*)d_in[7];
    const float* deliver_h = (const float*)d_in[8];
    const int* pair_v = (const int*)d_in[9];
    const int* pair_e = (const int*)d_in[10];
    const int* ec_map = (const int*)d_in[11];
    const int* ecd_map= (const int*)d_in[12];
    const float* e_table  = (const float*)d_in[13];
    const float* c_table  = (const float*)d_in[14];
    const float* ed_table = (const float*)d_in[15];
    const float* cd_table = (const float*)d_in[16];
    const float* a_table  = (const float*)d_in[17];
    const float* it_table = (const float*)d_in[18];
    const float* ep_table = (const float*)d_in[19];
    const float* ha_table = (const float*)d_in[20];
    const float* ca_table = (const float*)d_in[21];
    const float* as_table = (const float*)d_in[22];
    const float* W1 = (const float*)d_in[23];
    const float* b1 = (const float*)d_in[24];
    const float* g1 = (const float*)d_in[25];
    const float* be1= (const float*)d_in[26];
    const float* m1 = (const float*)d_in[27];
    const float* v1 = (const float*)d_in[28];
    const float* W2 = (const float*)d_in[29];
    const float* b2 = (const float*)d_in[30];
    const float* g2 = (const float*)d_in[31];
    const float* be2= (const float*)d_in[32];
    const float* m2 = (const float*)d_in[33];
    const float* v2 = (const float*)d_in[34];
    const float* Wi = (const float*)d_in[35];
    const float* bi = (const float*)d_in[36];
    const float* Wg = (const float*)d_in[37];
    const float* Ug = (const float*)d_in[38];
    const float* bg = (const float*)d_in[39];
    const float* We = (const float*)d_in[40];
    const float* beo= (const float*)d_in[41];
    const float* Ws = (const float*)d_in[42];
    const float* bs = (const float*)d_in[43];
    float* out = (float*)d_out;
    char* ws = (char*)d_ws;

    size_t off = 0;
    auto alloc = [&](size_t bytes) { size_t o = off; off += (bytes + 255) & ~(size_t)255; return o; };
    size_t o_degcur = alloc(378 * 4);            // e_deg[189] + cursor[189]
    size_t o_start  = alloc(190 * 4);
    size_t o_list   = alloc((size_t)NPAIR * 4);
    size_t o_aff    = alloc(512 * 4);
    size_t o_W1T    = alloc(16384 * 2);
    size_t o_W2T    = alloc(16384 * 2);
    size_t o_WiTe   = alloc(16384 * 2);
    size_t o_WgT    = alloc(49152 * 2);
    size_t o_UgT    = alloc(49152 * 2);
    size_t o_edW    = alloc(101 * 128 * 4);
    size_t o_epW    = alloc(101 * 128 * 4);
    size_t o_cW     = alloc(189 * 128 * 4);
    size_t o_cdW    = alloc(101 * 128 * 4);
    size_t o_agi    = alloc(2 * 384 * 4);
    size_t o_sd     = alloc(38 * 4);
    size_t o_etb    = alloc((size_t)N_V * DD * 2);
    size_t o_E      = alloc((size_t)N_HE * DD * 4);
    size_t o_Y      = alloc((size_t)N_V * DD * 4);
    size_t o_X1     = alloc((size_t)N_V * DD * 2);
    size_t o_X2     = alloc((size_t)N_V * DD * 2);
    size_t o_XW     = alloc((size_t)N_V * DD * 4);
    size_t o_xbf    = alloc((size_t)BSR * DD * 2);
    size_t o_gi     = alloc((size_t)BSR * 384 * 4);

    int*    e_deg  = (int*)(ws + o_degcur);
    int*    cursor = e_deg + 189;
    int*    startp = (int*)(ws + o_start);
    int*    listp  = (int*)(ws + o_list);
    float*  aff    = (float*)(ws + o_aff);
    ushort* W1T    = (ushort*)(ws + o_W1T);
    ushort* W2T    = (ushort*)(ws + o_W2T);
    ushort* WiTe   = (ushort*)(ws + o_WiTe);
    ushort* WgT    = (ushort*)(ws + o_WgT);
    ushort* UgTp   = (ushort*)(ws + o_UgT);
    float*  edW    = (float*)(ws + o_edW);
    float*  epW    = (float*)(ws + o_epW);
    float*  cW     = (float*)(ws + o_cW);
    float*  cdW    = (float*)(ws + o_cdW);
    float*  agi    = (float*)(ws + o_agi);
    float*  sd     = (float*)(ws + o_sd);
    ushort* e_tb   = (ushort*)(ws + o_etb);
    float*  E      = (float*)(ws + o_E);
    float*  Y      = (float*)(ws + o_Y);
    ushort* X1b    = (ushort*)(ws + o_X1);
    ushort* X2b    = (ushort*)(ws + o_X2);
    float*  XW     = (float*)(ws + o_XW);
    ushort* xbf    = (ushort*)(ws + o_xbf);
    float*  gi     = (float*)(ws + o_gi);

    hipMemsetAsync(ws + o_degcur, 0, 378 * 4, stream);

    P1Args pa;
    pa.pair_e = pair_e;
    pa.b1 = b1; pa.g1 = g1; pa.be1 = be1; pa.m1 = m1; pa.v1 = v1;
    pa.b2 = b2; pa.g2 = g2; pa.be2 = be2; pa.m2 = m2; pa.v2 = v2;
    pa.W1 = W1; pa.W2 = W2; pa.Wi = Wi; pa.Wg = Wg; pa.Ug = Ug;
    pa.ed_t = ed_table; pa.ep_t = ep_table; pa.c_t = c_table; pa.cd_t = cd_table;
    pa.a_t = a_table; pa.bi = bi; pa.bg = bg;
    pa.ha_t = ha_table; pa.ca_t = ca_table; pa.as_t = as_table; pa.it_t = it_table; pa.Ws = Ws;
    pa.e_deg = e_deg; pa.aff = aff;
    pa.W1T = W1T; pa.W2T = W2T; pa.WiTe = WiTe; pa.WgT = WgT; pa.UgT = UgTp;
    pa.edW = edW; pa.epW = epW; pa.cW = cW; pa.cdW = cdW; pa.agi = agi; pa.sd = sd;
    p1_kernel<<<1012, 384, 0, stream>>>(pa);

    cvt_kernel<<<(N_V * DD + 255) / 256, 256, 0, stream>>>(e_table, e_tb, N_V * DD);
    csr_prefix<<<1, 256, 0, stream>>>(e_deg, startp);
    csr_fill<<<94, 384, 0, stream>>>(pair_e, pair_v, startp, cursor, listp);

    pred_s_kernel<<<(BSR + 255) / 256, 256, 0, stream>>>(in_ha, in_ca, in_as, in_it, sd, bs, out);

    // conv1: Y = BN1(e_table @ W1 + b1)
    gemm_mfma<8><<<(N_V + 63) / 64, 256, 0, stream>>>(e_tb, W1T, Y, N_V, aff, aff + 128,
                                                      nullptr, nullptr);
    edge_mean<<<N_HE, 512, 0, stream>>>(Y, listp, startp, E);
    v_mean<<<(N_V * DD + 255) / 256, 256, 0, stream>>>(E, pair_e, X1b, 1);
    // conv2
    gemm_mfma<8><<<(N_V + 63) / 64, 256, 0, stream>>>(X1b, W2T, Y, N_V, aff + 256, aff + 384,
                                                      nullptr, nullptr);
    edge_mean<<<N_HE, 512, 0, stream>>>(Y, listp, startp, E);
    v_mean<<<(N_V * DD + 255) / 256, 256, 0, stream>>>(E, pair_e, X2b, 0);
    // XW = X2 @ Wi_e
    gemm_mfma<8><<<(N_V + 63) / 64, 256, 0, stream>>>(X2b, WiTe, XW, N_V, nullptr, nullptr,
                                                      nullptr, nullptr);
    // x = tanh(5-way gather sum)
    k3_kernel<<<(BSR * DD + 255) / 256, 256, 0, stream>>>(in_e, in_ed, in_ep, XW, cW, cdW, edW,
                                                          epW, ec_map, ecd_map, xbf);
    // gi = x @ Wg_x + a_gi[input_a]
    gemm_mfma<24><<<BSR / 64, 256, 0, stream>>>(xbf, WgT, gi, BSR, nullptr, nullptr, agi, in_a);
    // GRU scan + pred_main
    gru_scan<<<BB, 768, 0, stream>>>(gi, xbf, UgTp, deliver_h, We, beo, out);
}